// Round 4
// baseline (239.026 us; speedup 1.0000x reference)
//
#include <hip/hip_runtime.h>
#include <hip/hip_bf16.h>

typedef __bf16 bf16x8 __attribute__((ext_vector_type(8)));
typedef float f32x4 __attribute__((ext_vector_type(4)));
typedef float f32x16 __attribute__((ext_vector_type(16)));
typedef unsigned int uint32x4v __attribute__((ext_vector_type(4)));

#define B_ 2
#define T_ 2048
#define EMB_ 1024
#define H_ 16
#define D_ 64
#define M_ (B_ * T_)        // 4096
#define NQKV_ (3 * H_ * D_) // 3072

// 0.125 (=1/sqrt(64)) * log2(e): folded into Q so softmax runs in exp2 domain
#define QSCALE 0.18033688011112042f

#define GPTR(p) ((const __attribute__((address_space(1))) unsigned int*)(p))
#define LPTR(p) ((__attribute__((address_space(3))) unsigned int*)(p))

__device__ __forceinline__ unsigned pk2(float a, float b) {
    unsigned short ua = __builtin_bit_cast(unsigned short, (__bf16)a);
    unsigned short ub = __builtin_bit_cast(unsigned short, (__bf16)b);
    return (unsigned)ua | ((unsigned)ub << 16);
}

// ---------------- cast x fp32 -> bf16 ----------------
__global__ void cast_bf16_k(const float* __restrict__ in, __bf16* __restrict__ out) {
    int i = (blockIdx.x * blockDim.x + threadIdx.x) * 8;
    float4 a = *reinterpret_cast<const float4*>(in + i);
    float4 b = *reinterpret_cast<const float4*>(in + i + 4);
    bf16x8 o;
    o[0] = (__bf16)a.x; o[1] = (__bf16)a.y; o[2] = (__bf16)a.z; o[3] = (__bf16)a.w;
    o[4] = (__bf16)b.x; o[5] = (__bf16)b.y; o[6] = (__bf16)b.z; o[7] = (__bf16)b.w;
    *reinterpret_cast<bf16x8*>(out + i) = o;
}

// ---------------- transpose + cast: in [K][N] fp32 -> out [N][K] bf16 ----------------
__global__ void transpose_cast_k(const float* __restrict__ in, __bf16* __restrict__ out,
                                 int K, int N) {
    __shared__ float tile[32][33];
    int bx = blockIdx.x;  // over N
    int by = blockIdx.y;  // over K
    int tx = threadIdx.x, ty = threadIdx.y;  // 32 x 8
    for (int j = 0; j < 32; j += 8)
        tile[ty + j][tx] = in[(size_t)(by * 32 + ty + j) * N + bx * 32 + tx];
    __syncthreads();
    for (int j = 0; j < 32; j += 8)
        out[(size_t)(bx * 32 + ty + j) * K + by * 32 + tx] = (__bf16)tile[tx][ty + j];
}

// ---------------- GEMM: A[M][K] bf16, Bt[N][K] bf16, bias fp32 ----------------
// 2-phase double-buffered global_load_lds staging + both-sides XOR chunk swizzle.
// EPI 0: outF = acc + bias (fp32). EPI 1: qkv scatter (Q scaled by QSCALE).
#define BM 128
#define BN 128
#define BK 64

template <int EPI>
__global__ __launch_bounds__(256, 2) void gemm_bf16_k(
    const __bf16* __restrict__ A, const __bf16* __restrict__ Bt,
    const float* __restrict__ bias, float* __restrict__ outF,
    __bf16* __restrict__ Qg, __bf16* __restrict__ Kg, __bf16* __restrict__ Vtg,
    int Mdim, int Ndim, int Kdim) {
    __shared__ __bf16 As[2][BM * BK];
    __shared__ __bf16 Bs[2][BN * BK];
    const int tid = threadIdx.x;
    const int lane = tid & 63;
    const int w = tid >> 6;
    const int wr = w >> 1, wc = w & 1;
    const int row0 = blockIdx.y * BM;
    const int col0 = blockIdx.x * BN;
    const int lr = lane & 15;
    const int lg = lane >> 4;

    f32x4 acc[4][4] = {};

    const int srow = 32 * w;                 // this wave's staging row block base
    const int lrow = lane >> 3;              // 0..7 within 8-row group
    const int scc = ((lane & 7) ^ (lrow & 7)) * 8;  // pre-swizzled source chunk

    auto STAGE = [&](int t, int bufi) {
        const int k0 = t * BK;
        #pragma unroll
        for (int i = 0; i < 4; ++i) {
            int r0 = srow + 8 * i;
            int row = r0 + lrow;
            __builtin_amdgcn_global_load_lds(
                GPTR(A + (size_t)(row0 + row) * Kdim + k0 + scc), LPTR(&As[bufi][r0 * BK]), 16, 0, 0);
            __builtin_amdgcn_global_load_lds(
                GPTR(Bt + (size_t)(col0 + row) * Kdim + k0 + scc), LPTR(&Bs[bufi][r0 * BK]), 16, 0, 0);
        }
    };

    const int nk = Kdim / BK;
    STAGE(0, 0);
    __syncthreads();
    for (int t = 0; t < nk; ++t) {
        if (t + 1 < nk) STAGE(t + 1, (t + 1) & 1);
        const __bf16* __restrict__ Ab = As[t & 1];
        const __bf16* __restrict__ Bb = Bs[t & 1];
        #pragma unroll
        for (int kk = 0; kk < BK; kk += 32) {
            bf16x8 af[4], bfr[4];
            #pragma unroll
            for (int mt = 0; mt < 4; ++mt) {
                int row = wr * 64 + mt * 16 + lr;
                int cc = ((kk / 8 + lg) ^ (row & 7)) * 8;
                af[mt] = *reinterpret_cast<const bf16x8*>(&Ab[row * BK + cc]);
            }
            #pragma unroll
            for (int nt = 0; nt < 4; ++nt) {
                int row = wc * 64 + nt * 16 + lr;
                int cc = ((kk / 8 + lg) ^ (row & 7)) * 8;
                bfr[nt] = *reinterpret_cast<const bf16x8*>(&Bb[row * BK + cc]);
            }
            #pragma unroll
            for (int mt = 0; mt < 4; ++mt)
                #pragma unroll
                for (int nt = 0; nt < 4; ++nt)
                    acc[mt][nt] = __builtin_amdgcn_mfma_f32_16x16x32_bf16(
                        af[mt], bfr[nt], acc[mt][nt], 0, 0, 0);
        }
        __syncthreads();
    }

    #pragma unroll
    for (int mt = 0; mt < 4; ++mt)
        #pragma unroll
        for (int nt = 0; nt < 4; ++nt)
            #pragma unroll
            for (int r = 0; r < 4; ++r) {
                int row = row0 + wr * 64 + mt * 16 + lg * 4 + r;
                int col = col0 + wc * 64 + nt * 16 + lr;
                float v = acc[mt][nt][r] + bias[col];
                if (EPI == 0) {
                    outF[(size_t)row * Ndim + col] = v;
                } else {
                    int part = col >> 10;
                    int hh = (col >> 6) & 15;
                    int dd = col & 63;
                    int bb = row >> 11;
                    int tt = row & 2047;
                    size_t bh = (size_t)(bb * H_ + hh);
                    if (part == 0)
                        Qg[(bh * T_ + tt) * D_ + dd] = (__bf16)(v * QSCALE);
                    else if (part == 1)
                        Kg[(bh * T_ + tt) * D_ + dd] = (__bf16)v;
                    else
                        Vtg[(bh * D_ + dd) * T_ + tt] = (__bf16)v;
                }
            }
}

// ---------------- causal flash attention: 1 wave = 32 q rows, no LDS, no barriers ----
#define KVB 64

template <bool MASK>
__device__ __forceinline__ void attn_tile(
    const bf16x8 (&qf)[4], const bf16x8 (&k0)[4], const bf16x8 (&k1)[4],
    const bf16x8 (&v0)[4], const bf16x8 (&v1)[4],
    f32x16& o0, f32x16& o1, float& m, float& lsum, int thr, int hi) {
    f32x16 s0 = {}, s1 = {};
    __builtin_amdgcn_s_setprio(1);
    #pragma unroll
    for (int ks = 0; ks < 4; ++ks) {
        s0 = __builtin_amdgcn_mfma_f32_32x32x16_bf16(k0[ks], qf[ks], s0, 0, 0, 0);
        s1 = __builtin_amdgcn_mfma_f32_32x32x16_bf16(k1[ks], qf[ks], s1, 0, 0, 0);
    }
    __builtin_amdgcn_s_setprio(0);
    if (MASK) {
        #pragma unroll
        for (int r = 0; r < 16; ++r) {
            int c = (r & 3) + 8 * (r >> 2);
            if (c > thr) s0[r] = -1e30f;
            if (c + 32 > thr) s1[r] = -1e30f;
        }
    }
    // row max: in-lane + one cross-half exchange (proven shfl_xor path)
    float pmax = -1e30f;
    #pragma unroll
    for (int r = 0; r < 16; ++r) pmax = fmaxf(pmax, fmaxf(s0[r], s1[r]));
    pmax = fmaxf(pmax, __shfl_xor(pmax, 32, 64));
    // defer-max rescale (THR=8 in log2 domain)
    if (__any(pmax > m + 8.f)) {
        float mnew = fmaxf(m, pmax);
        float corr = __builtin_exp2f(m - mnew);
        m = mnew;
        lsum *= corr;
        #pragma unroll
        for (int r = 0; r < 16; ++r) {
            int qsrc = (r & 3) + 8 * (r >> 2) + 4 * hi;
            float cb = __shfl(corr, qsrc, 64);
            o0[r] *= cb; o1[r] *= cb;
        }
    }
    // P = exp2(S - m), row sum
    float ps = 0.f;
    #pragma unroll
    for (int r = 0; r < 16; ++r) {
        s0[r] = __builtin_exp2f(s0[r] - m);
        s1[r] = __builtin_exp2f(s1[r] - m);
        ps += s0[r] + s1[r];
    }
    ps += __shfl_xor(ps, 32, 64);
    lsum += ps;
    // P -> bf16 A-frags (cross-half exchange via shfl_xor) + PV
    #pragma unroll
    for (int ks = 0; ks < 4; ++ks) {
        const int e = (ks & 1) * 8;
        unsigned w0, w1, w2, w3;
        if (ks < 2) {
            w0 = pk2(s0[e + 0], s0[e + 1]); w1 = pk2(s0[e + 2], s0[e + 3]);
            w2 = pk2(s0[e + 4], s0[e + 5]); w3 = pk2(s0[e + 6], s0[e + 7]);
        } else {
            w0 = pk2(s1[e + 0], s1[e + 1]); w1 = pk2(s1[e + 2], s1[e + 3]);
            w2 = pk2(s1[e + 4], s1[e + 5]); w3 = pk2(s1[e + 6], s1[e + 7]);
        }
        unsigned pw0 = __shfl_xor(w0, 32, 64);
        unsigned pw1 = __shfl_xor(w1, 32, 64);
        unsigned pw2 = __shfl_xor(w2, 32, 64);
        unsigned pw3 = __shfl_xor(w3, 32, 64);
        uint32x4v uf;
        uf.x = hi ? pw2 : w0;
        uf.y = hi ? pw3 : w1;
        uf.z = hi ? w2 : pw0;
        uf.w = hi ? w3 : pw1;
        bf16x8 pa = __builtin_bit_cast(bf16x8, uf);
        __builtin_amdgcn_s_setprio(1);
        o0 = __builtin_amdgcn_mfma_f32_32x32x16_bf16(pa, v0[ks], o0, 0, 0, 0);
        o1 = __builtin_amdgcn_mfma_f32_32x32x16_bf16(pa, v1[ks], o1, 0, 0, 0);
        __builtin_amdgcn_s_setprio(0);
    }
}

__global__ __launch_bounds__(64, 2) void attn_k(
    const __bf16* __restrict__ Qg, const __bf16* __restrict__ Kg,
    const __bf16* __restrict__ Vtg, __bf16* __restrict__ Og) {
    const int lane = threadIdx.x;
    const int l31 = lane & 31;
    const int hi = lane >> 5;
    const int bid = blockIdx.x;        // 2048
    const int bh = bid & 31;
    const int qt = 63 - (bid >> 5);    // heavy first
    const int q0 = qt * 32;
    const int q_lane = q0 + l31;
    const int nt = (qt >> 1) + 1;      // KVB=64 tiles
    const size_t baseQK = (size_t)bh * T_ * D_;
    const size_t baseVt = (size_t)bh * D_ * T_;

    // Q B-frags (pre-scaled by QSCALE at the QKV epilogue)
    bf16x8 qf[4];
    #pragma unroll
    for (int ks = 0; ks < 4; ++ks)
        qf[ks] = *reinterpret_cast<const bf16x8*>(
            &Qg[baseQK + (size_t)q_lane * D_ + ks * 16 + hi * 8]);

    // per-lane fragment base pointers
    const __bf16* kp0 = Kg + baseQK + (size_t)l31 * D_ + hi * 8;
    const __bf16* kp1 = kp0 + 32 * D_;
    const __bf16* vp0 = Vtg + baseVt + (size_t)l31 * T_ + hi * 8;

    f32x16 o0 = {}, o1 = {};
    float m = -1e30f, lsum = 0.f;

    // K frags for tile 0
    bf16x8 ka0[4], ka1[4];
    #pragma unroll
    for (int ks = 0; ks < 4; ++ks) {
        ka0[ks] = *reinterpret_cast<const bf16x8*>(kp0 + ks * 16);
        ka1[ks] = *reinterpret_cast<const bf16x8*>(kp1 + ks * 16);
    }

    // main loop: unmasked tiles, V(t) + K(t+1) issued up front
    for (int t = 0; t < nt - 1; ++t) {
        bf16x8 v0[4], v1[4], kn0[4], kn1[4];
        const __bf16* vt = vp0 + t * KVB;
        const __bf16* kt = kp0 + (size_t)(t + 1) * KVB * D_;
        #pragma unroll
        for (int ks = 0; ks < 4; ++ks) {
            v0[ks] = *reinterpret_cast<const bf16x8*>(vt + ks * 16);
            v1[ks] = *reinterpret_cast<const bf16x8*>(vt + (size_t)32 * T_ + ks * 16);
            kn0[ks] = *reinterpret_cast<const bf16x8*>(kt + ks * 16);
            kn1[ks] = *reinterpret_cast<const bf16x8*>(kt + 32 * D_ + ks * 16);
        }
        attn_tile<false>(qf, ka0, ka1, v0, v1, o0, o1, m, lsum, 0, hi);
        #pragma unroll
        for (int ks = 0; ks < 4; ++ks) { ka0[ks] = kn0[ks]; ka1[ks] = kn1[ks]; }
    }
    // diagonal tile
    {
        const int t = nt - 1;
        bf16x8 v0[4], v1[4];
        const __bf16* vt = vp0 + t * KVB;
        #pragma unroll
        for (int ks = 0; ks < 4; ++ks) {
            v0[ks] = *reinterpret_cast<const bf16x8*>(vt + ks * 16);
            v1[ks] = *reinterpret_cast<const bf16x8*>(vt + (size_t)32 * T_ + ks * 16);
        }
        attn_tile<true>(qf, ka0, ka1, v0, v1, o0, o1, m, lsum,
                        q_lane - t * KVB - 4 * hi, hi);
    }

    // epilogue: O /= lsum, write Og[b*t][h*64+d]
    const int b = bh >> 4, h = bh & 15;
    float li = 1.0f / lsum;
    #pragma unroll
    for (int r = 0; r < 16; ++r) {
        int qsrc = (r & 3) + 8 * (r >> 2) + 4 * hi;
        float cb = __shfl(li, qsrc, 64);
        int tt = q0 + qsrc;
        size_t base = (size_t)(b * T_ + tt) * (H_ * D_) + h * D_;
        Og[base + l31]      = (__bf16)(o0[r] * cb);
        Og[base + 32 + l31] = (__bf16)(o1[r] * cb);
    }
}

// ---------------- launch ----------------
extern "C" void kernel_launch(void* const* d_in, const int* in_sizes, int n_in,
                              void* d_out, int out_size, void* d_ws, size_t ws_size,
                              hipStream_t stream) {
    const float* x    = (const float*)d_in[0];
    const float* Wqkv = (const float*)d_in[1];
    const float* bqkv = (const float*)d_in[2];
    const float* Wout = (const float*)d_in[3];
    const float* bout = (const float*)d_in[4];
    float* outF = (float*)d_out;

    char* ws = (char*)d_ws;
    __bf16* xb     = (__bf16*)(ws);                       // 4096x1024
    __bf16* WqkvT  = (__bf16*)(ws + 8388608);             // 3072x1024
    __bf16* WoutT  = (__bf16*)(ws + 14680064);            // 1024x1024
    __bf16* Qg     = (__bf16*)(ws + 16777216);            // [b,h,t,d] (pre-scaled)
    __bf16* Kg     = (__bf16*)(ws + 25165824);            // [b,h,t,d]
    __bf16* Vtg    = (__bf16*)(ws + 33554432);            // [b,h,d,t]
    __bf16* Og     = (__bf16*)(ws + 41943040);            // [b*t][h*d]

    cast_bf16_k<<<(M_ * EMB_) / (256 * 8), 256, 0, stream>>>(x, xb);
    transpose_cast_k<<<dim3(NQKV_ / 32, EMB_ / 32), dim3(32, 8), 0, stream>>>(Wqkv, WqkvT, EMB_, NQKV_);
    transpose_cast_k<<<dim3(EMB_ / 32, EMB_ / 32), dim3(32, 8), 0, stream>>>(Wout, WoutT, EMB_, EMB_);

    gemm_bf16_k<1><<<dim3(NQKV_ / BN, M_ / BM), 256, 0, stream>>>(
        xb, WqkvT, bqkv, nullptr, Qg, Kg, Vtg, M_, NQKV_, EMB_);

    attn_k<<<2048, 64, 0, stream>>>(Qg, Kg, Vtg, Og);

    gemm_bf16_k<0><<<dim3(EMB_ / BN, M_ / BM), 256, 0, stream>>>(
        Og, WoutT, bout, outF, nullptr, nullptr, nullptr, M_, EMB_, EMB_);
}

// Round 6
// 221.418 us; speedup vs baseline: 1.0795x; 1.0795x over previous
//
#include <hip/hip_runtime.h>
#include <hip/hip_bf16.h>

typedef __bf16 bf16x8 __attribute__((ext_vector_type(8)));
typedef float f32x4 __attribute__((ext_vector_type(4)));
typedef float f32x16 __attribute__((ext_vector_type(16)));
typedef unsigned int uint32x4v __attribute__((ext_vector_type(4)));

#define B_ 2
#define T_ 2048
#define EMB_ 1024
#define H_ 16
#define D_ 64
#define M_ (B_ * T_)        // 4096
#define NQKV_ (3 * H_ * D_) // 3072

// 0.125 (=1/sqrt(64)) * log2(e): folded into Q so softmax runs in exp2 domain
#define QSCALE 0.18033688011112042f

#define GPTR(p) ((const __attribute__((address_space(1))) unsigned int*)(p))
#define LPTR(p) ((__attribute__((address_space(3))) unsigned int*)(p))

__device__ __forceinline__ unsigned pk2(float a, float b) {
    unsigned short ua = __builtin_bit_cast(unsigned short, (__bf16)a);
    unsigned short ub = __builtin_bit_cast(unsigned short, (__bf16)b);
    return (unsigned)ua | ((unsigned)ub << 16);
}

// ---------------- cast x fp32 -> bf16 ----------------
__global__ void cast_bf16_k(const float* __restrict__ in, __bf16* __restrict__ out) {
    int i = (blockIdx.x * blockDim.x + threadIdx.x) * 8;
    float4 a = *reinterpret_cast<const float4*>(in + i);
    float4 b = *reinterpret_cast<const float4*>(in + i + 4);
    bf16x8 o;
    o[0] = (__bf16)a.x; o[1] = (__bf16)a.y; o[2] = (__bf16)a.z; o[3] = (__bf16)a.w;
    o[4] = (__bf16)b.x; o[5] = (__bf16)b.y; o[6] = (__bf16)b.z; o[7] = (__bf16)b.w;
    *reinterpret_cast<bf16x8*>(out + i) = o;
}

// ---------------- transpose + cast: in [K][N] fp32 -> out [N][K] bf16 ----------------
__global__ void transpose_cast_k(const float* __restrict__ in, __bf16* __restrict__ out,
                                 int K, int N) {
    __shared__ float tile[32][33];
    int bx = blockIdx.x;  // over N
    int by = blockIdx.y;  // over K
    int tx = threadIdx.x, ty = threadIdx.y;  // 32 x 8
    for (int j = 0; j < 32; j += 8)
        tile[ty + j][tx] = in[(size_t)(by * 32 + ty + j) * N + bx * 32 + tx];
    __syncthreads();
    for (int j = 0; j < 32; j += 8)
        out[(size_t)(bx * 32 + ty + j) * K + by * 32 + tx] = (__bf16)tile[tx][ty + j];
}

// ---------------- GEMM: A[M][K] bf16, Bt[N][K] bf16, bias fp32 ----------------
// 2-phase double-buffered global_load_lds staging + both-sides XOR chunk swizzle.
// EPI 0: outF = acc + bias (fp32). EPI 1: qkv scatter (Q scaled by QSCALE).
#define BM 128
#define BN 128
#define BK 64

template <int EPI>
__global__ __launch_bounds__(256, 2) void gemm_bf16_k(
    const __bf16* __restrict__ A, const __bf16* __restrict__ Bt,
    const float* __restrict__ bias, float* __restrict__ outF,
    __bf16* __restrict__ Qg, __bf16* __restrict__ Kg, __bf16* __restrict__ Vtg,
    int Mdim, int Ndim, int Kdim) {
    __shared__ __bf16 As[2][BM * BK];
    __shared__ __bf16 Bs[2][BN * BK];
    const int tid = threadIdx.x;
    const int lane = tid & 63;
    const int w = tid >> 6;
    const int wr = w >> 1, wc = w & 1;
    const int row0 = blockIdx.y * BM;
    const int col0 = blockIdx.x * BN;
    const int lr = lane & 15;
    const int lg = lane >> 4;

    f32x4 acc[4][4] = {};

    const int srow = 32 * w;                 // this wave's staging row block base
    const int lrow = lane >> 3;              // 0..7 within 8-row group
    const int scc = ((lane & 7) ^ (lrow & 7)) * 8;  // pre-swizzled source chunk

    auto STAGE = [&](int t, int bufi) {
        const int k0 = t * BK;
        #pragma unroll
        for (int i = 0; i < 4; ++i) {
            int r0 = srow + 8 * i;
            int row = r0 + lrow;
            __builtin_amdgcn_global_load_lds(
                GPTR(A + (size_t)(row0 + row) * Kdim + k0 + scc), LPTR(&As[bufi][r0 * BK]), 16, 0, 0);
            __builtin_amdgcn_global_load_lds(
                GPTR(Bt + (size_t)(col0 + row) * Kdim + k0 + scc), LPTR(&Bs[bufi][r0 * BK]), 16, 0, 0);
        }
    };

    const int nk = Kdim / BK;
    STAGE(0, 0);
    __syncthreads();
    for (int t = 0; t < nk; ++t) {
        if (t + 1 < nk) STAGE(t + 1, (t + 1) & 1);
        const __bf16* __restrict__ Ab = As[t & 1];
        const __bf16* __restrict__ Bb = Bs[t & 1];
        #pragma unroll
        for (int kk = 0; kk < BK; kk += 32) {
            bf16x8 af[4], bfr[4];
            #pragma unroll
            for (int mt = 0; mt < 4; ++mt) {
                int row = wr * 64 + mt * 16 + lr;
                int cc = ((kk / 8 + lg) ^ (row & 7)) * 8;
                af[mt] = *reinterpret_cast<const bf16x8*>(&Ab[row * BK + cc]);
            }
            #pragma unroll
            for (int nt = 0; nt < 4; ++nt) {
                int row = wc * 64 + nt * 16 + lr;
                int cc = ((kk / 8 + lg) ^ (row & 7)) * 8;
                bfr[nt] = *reinterpret_cast<const bf16x8*>(&Bb[row * BK + cc]);
            }
            #pragma unroll
            for (int mt = 0; mt < 4; ++mt)
                #pragma unroll
                for (int nt = 0; nt < 4; ++nt)
                    acc[mt][nt] = __builtin_amdgcn_mfma_f32_16x16x32_bf16(
                        af[mt], bfr[nt], acc[mt][nt], 0, 0, 0);
        }
        __syncthreads();
    }

    #pragma unroll
    for (int mt = 0; mt < 4; ++mt)
        #pragma unroll
        for (int nt = 0; nt < 4; ++nt)
            #pragma unroll
            for (int r = 0; r < 4; ++r) {
                int row = row0 + wr * 64 + mt * 16 + lg * 4 + r;
                int col = col0 + wc * 64 + nt * 16 + lr;
                float v = acc[mt][nt][r] + bias[col];
                if (EPI == 0) {
                    outF[(size_t)row * Ndim + col] = v;
                } else {
                    int part = col >> 10;
                    int hh = (col >> 6) & 15;
                    int dd = col & 63;
                    int bb = row >> 11;
                    int tt = row & 2047;
                    size_t bh = (size_t)(bb * H_ + hh);
                    if (part == 0)
                        Qg[(bh * T_ + tt) * D_ + dd] = (__bf16)(v * QSCALE);
                    else if (part == 1)
                        Kg[(bh * T_ + tt) * D_ + dd] = (__bf16)v;
                    else
                        Vtg[(bh * D_ + dd) * T_ + tt] = (__bf16)v;
                }
            }
}

// ---------------- causal flash attention ----------------
// 2 waves/block, 64 q-rows/block, KVB=64, double-buffered LDS K/V staging,
// in-register exp2-domain softmax (round-4 verified), XOR-chunk swizzle.
#define KVB 64
#define QBLK 64

template <bool MASK>
__device__ __forceinline__ void attn_tile(
    const bf16x8 (&qf)[4], const __bf16* __restrict__ Ksb, const __bf16* __restrict__ Vsb,
    f32x16& o0, f32x16& o1, float& m, float& lsum, int thr, int hi, int l31) {
    const int cb = l31 & 7;
    bf16x8 kf0[4], kf1[4];
    #pragma unroll
    for (int ks = 0; ks < 4; ++ks) {
        int c = ((2 * ks + hi) ^ cb) * 8;
        kf0[ks] = *reinterpret_cast<const bf16x8*>(&Ksb[l31 * 64 + c]);
        kf1[ks] = *reinterpret_cast<const bf16x8*>(&Ksb[(32 + l31) * 64 + c]);
    }
    f32x16 s0 = {}, s1 = {};
    __builtin_amdgcn_s_setprio(1);
    #pragma unroll
    for (int ks = 0; ks < 4; ++ks) {
        s0 = __builtin_amdgcn_mfma_f32_32x32x16_bf16(kf0[ks], qf[ks], s0, 0, 0, 0);
        s1 = __builtin_amdgcn_mfma_f32_32x32x16_bf16(kf1[ks], qf[ks], s1, 0, 0, 0);
    }
    __builtin_amdgcn_s_setprio(0);
    if (MASK) {
        #pragma unroll
        for (int r = 0; r < 16; ++r) {
            int c = (r & 3) + 8 * (r >> 2);
            if (c > thr) s0[r] = -1e30f;
            if (c + 32 > thr) s1[r] = -1e30f;
        }
    }
    // row max: in-lane + one cross-half exchange
    float pmax = -1e30f;
    #pragma unroll
    for (int r = 0; r < 16; ++r) pmax = fmaxf(pmax, fmaxf(s0[r], s1[r]));
    pmax = fmaxf(pmax, __shfl_xor(pmax, 32, 64));
    // defer-max rescale (THR=8 in log2 domain)
    if (__any(pmax > m + 8.f)) {
        float mnew = fmaxf(m, pmax);
        float corr = __builtin_exp2f(m - mnew);
        m = mnew;
        lsum *= corr;
        #pragma unroll
        for (int r = 0; r < 16; ++r) {
            int qsrc = (r & 3) + 8 * (r >> 2) + 4 * hi;
            float cbr = __shfl(corr, qsrc, 64);
            o0[r] *= cbr; o1[r] *= cbr;
        }
    }
    // P = exp2(S - m), row sum
    float ps = 0.f;
    #pragma unroll
    for (int r = 0; r < 16; ++r) {
        s0[r] = __builtin_exp2f(s0[r] - m);
        s1[r] = __builtin_exp2f(s1[r] - m);
        ps += s0[r] + s1[r];
    }
    ps += __shfl_xor(ps, 32, 64);
    lsum += ps;
    // P -> bf16 A-frags (cross-half exchange via shfl_xor) + PV
    #pragma unroll
    for (int ks = 0; ks < 4; ++ks) {
        const int e = (ks & 1) * 8;
        unsigned w0, w1, w2, w3;
        if (ks < 2) {
            w0 = pk2(s0[e + 0], s0[e + 1]); w1 = pk2(s0[e + 2], s0[e + 3]);
            w2 = pk2(s0[e + 4], s0[e + 5]); w3 = pk2(s0[e + 6], s0[e + 7]);
        } else {
            w0 = pk2(s1[e + 0], s1[e + 1]); w1 = pk2(s1[e + 2], s1[e + 3]);
            w2 = pk2(s1[e + 4], s1[e + 5]); w3 = pk2(s1[e + 6], s1[e + 7]);
        }
        unsigned pw0 = __shfl_xor(w0, 32, 64);
        unsigned pw1 = __shfl_xor(w1, 32, 64);
        unsigned pw2 = __shfl_xor(w2, 32, 64);
        unsigned pw3 = __shfl_xor(w3, 32, 64);
        uint32x4v uf;
        uf.x = hi ? pw2 : w0;
        uf.y = hi ? pw3 : w1;
        uf.z = hi ? w2 : pw0;
        uf.w = hi ? w3 : pw1;
        bf16x8 pa = __builtin_bit_cast(bf16x8, uf);
        int c = ((2 * ks + hi) ^ cb) * 8;
        bf16x8 vf0 = *reinterpret_cast<const bf16x8*>(&Vsb[l31 * 64 + c]);
        bf16x8 vf1 = *reinterpret_cast<const bf16x8*>(&Vsb[(32 + l31) * 64 + c]);
        __builtin_amdgcn_s_setprio(1);
        o0 = __builtin_amdgcn_mfma_f32_32x32x16_bf16(pa, vf0, o0, 0, 0, 0);
        o1 = __builtin_amdgcn_mfma_f32_32x32x16_bf16(pa, vf1, o1, 0, 0, 0);
        __builtin_amdgcn_s_setprio(0);
    }
}

__global__ __launch_bounds__(128, 2) void attn_k(
    const __bf16* __restrict__ Qg, const __bf16* __restrict__ Kg,
    const __bf16* __restrict__ Vtg, __bf16* __restrict__ Og) {
    __shared__ __bf16 Ks[2][KVB * 64];
    __shared__ __bf16 Vs[2][64 * KVB];

    const int tid = threadIdx.x;
    const int lane = tid & 63;
    const int w = tid >> 6;            // 0..1
    const int l31 = lane & 31;
    const int hi = lane >> 5;
    const int bid = blockIdx.x;        // 0..1023
    const int bh = bid & 31;
    const int idx = bid >> 5;          // 0..31
    const int qb = (idx < 16) ? (31 - idx) : (idx - 16);   // heavy first, paired
    const int q0 = qb * QBLK;
    const int qw = q0 + w * 32;
    const int q_lane = qw + l31;
    const int ntile = qb + 1;
    const size_t baseQK = (size_t)bh * T_ * D_;
    const size_t baseVt = (size_t)bh * D_ * T_;

    // staging geometry: per instr, a wave covers 8 rows x 64B swizzled chunks
    const int lrow = lane >> 3;                      // 0..7
    const int lc = lane & 7;

    auto STAGE = [&](int t, int bufi) {
        const int kv0 = t * KVB;
        #pragma unroll
        for (int i = 0; i < 4; ++i) {
            int r0 = i * 16 + w * 8;
            int row = r0 + lrow;
            int c = (lc ^ (row & 7)) * 8;
            __builtin_amdgcn_global_load_lds(
                GPTR(Kg + baseQK + (size_t)(kv0 + row) * D_ + c),
                LPTR(&Ks[bufi][r0 * 64]), 16, 0, 0);
            __builtin_amdgcn_global_load_lds(
                GPTR(Vtg + baseVt + (size_t)row * T_ + kv0 + c),
                LPTR(&Vs[bufi][r0 * 64]), 16, 0, 0);
        }
    };

    // Q B-frags (pre-scaled by QSCALE at the QKV epilogue)
    bf16x8 qf[4];
    #pragma unroll
    for (int ks = 0; ks < 4; ++ks)
        qf[ks] = *reinterpret_cast<const bf16x8*>(
            &Qg[baseQK + (size_t)q_lane * D_ + ks * 16 + hi * 8]);

    f32x16 o0 = {}, o1 = {};
    float m = -1e30f, lsum = 0.f;

    STAGE(0, 0);
    __syncthreads();
    // main loop: fully-unmasked tiles, prefetch next tile into other buffer
    for (int t = 0; t < ntile - 1; ++t) {
        STAGE(t + 1, (t + 1) & 1);
        attn_tile<false>(qf, Ks[t & 1], Vs[t & 1], o0, o1, m, lsum, 0, hi, l31);
        __syncthreads();
    }
    // diagonal tile
    attn_tile<true>(qf, Ks[(ntile - 1) & 1], Vs[(ntile - 1) & 1],
                    o0, o1, m, lsum, q_lane - (ntile - 1) * KVB - 4 * hi, hi, l31);

    // epilogue: O /= lsum, write Og[b*t][h*64+d]
    const int b = bh >> 4, h = bh & 15;
    float li = 1.0f / lsum;
    #pragma unroll
    for (int r = 0; r < 16; ++r) {
        int qsrc = (r & 3) + 8 * (r >> 2) + 4 * hi;
        float cbr = __shfl(li, qsrc, 64);
        int tt = qw + qsrc;
        size_t base = (size_t)(b * T_ + tt) * (H_ * D_) + h * D_;
        Og[base + l31]      = (__bf16)(o0[r] * cbr);
        Og[base + 32 + l31] = (__bf16)(o1[r] * cbr);
    }
}

// ---------------- launch ----------------
extern "C" void kernel_launch(void* const* d_in, const int* in_sizes, int n_in,
                              void* d_out, int out_size, void* d_ws, size_t ws_size,
                              hipStream_t stream) {
    const float* x    = (const float*)d_in[0];
    const float* Wqkv = (const float*)d_in[1];
    const float* bqkv = (const float*)d_in[2];
    const float* Wout = (const float*)d_in[3];
    const float* bout = (const float*)d_in[4];
    float* outF = (float*)d_out;

    char* ws = (char*)d_ws;
    __bf16* xb     = (__bf16*)(ws);                       // 4096x1024
    __bf16* WqkvT  = (__bf16*)(ws + 8388608);             // 3072x1024
    __bf16* WoutT  = (__bf16*)(ws + 14680064);            // 1024x1024
    __bf16* Qg     = (__bf16*)(ws + 16777216);            // [b,h,t,d] (pre-scaled)
    __bf16* Kg     = (__bf16*)(ws + 25165824);            // [b,h,t,d]
    __bf16* Vtg    = (__bf16*)(ws + 33554432);            // [b,h,d,t]
    __bf16* Og     = (__bf16*)(ws + 41943040);            // [b*t][h*d]

    cast_bf16_k<<<(M_ * EMB_) / (256 * 8), 256, 0, stream>>>(x, xb);
    transpose_cast_k<<<dim3(NQKV_ / 32, EMB_ / 32), dim3(32, 8), 0, stream>>>(Wqkv, WqkvT, EMB_, NQKV_);
    transpose_cast_k<<<dim3(EMB_ / 32, EMB_ / 32), dim3(32, 8), 0, stream>>>(Wout, WoutT, EMB_, EMB_);

    gemm_bf16_k<1><<<dim3(NQKV_ / BN, M_ / BM), 256, 0, stream>>>(
        xb, WqkvT, bqkv, nullptr, Qg, Kg, Vtg, M_, NQKV_, EMB_);

    attn_k<<<1024, 128, 0, stream>>>(Qg, Kg, Vtg, Og);

    gemm_bf16_k<0><<<dim3(EMB_ / BN, M_ / BM), 256, 0, stream>>>(
        Og, WoutT, bout, outF, nullptr, nullptr, nullptr, M_, EMB_, EMB_);
}